// Round 1
// baseline (258.777 us; speedup 1.0000x reference)
//
#include <hip/hip_runtime.h>
#include <math.h>

// GradientBoostingLoss: per-row top-4 hardest negatives + logsumexp loss, mean over rows.
// One 64-lane wave per row; float4 coalesced loads; butterfly top-4 merge.

#define WAVES_PER_BLOCK 4

__device__ __forceinline__ void ins4(float v, float &t0, float &t1, float &t2, float &t3) {
    // Branchless sorted-descending insert of v into (t0 >= t1 >= t2 >= t3).
    bool b0 = v > t0, b1 = v > t1, b2 = v > t2, b3 = v > t3;
    float n0 = b0 ? v  : t0;
    float n1 = b0 ? t0 : (b1 ? v : t1);
    float n2 = b1 ? t1 : (b2 ? v : t2);
    float n3 = b2 ? t2 : (b3 ? v : t3);
    t0 = n0; t1 = n1; t2 = n2; t3 = n3;
}

__global__ __launch_bounds__(256) void topk_hard_neg_loss_kernel(
    const float* __restrict__ logits, const int* __restrict__ labels,
    float* __restrict__ out, int B, int C, float invB)
{
    const int wid  = threadIdx.x >> 6;
    const int lane = threadIdx.x & 63;
    const int row  = blockIdx.x * WAVES_PER_BLOCK + wid;

    __shared__ float s_loss[WAVES_PER_BLOCK];

    float loss = 0.0f;
    if (row < B) {
        const float4* rp = (const float4*)(logits + (size_t)row * (size_t)C);
        const int nq  = C >> 2;               // 250 float4 per row (C=1000)
        const int L   = labels[row];
        const int qL  = L >> 2;
        const int sub = L & 3;

        float t0 = -INFINITY, t1 = -INFINITY, t2 = -INFINITY, t3 = -INFINITY;
        float lab = -INFINITY;

        for (int q = lane; q < nq; q += 64) {
            float4 v = rp[q];
            if (q == qL) {
                // Capture the true-label logit and exclude it from the top-k.
                lab = (sub == 0) ? v.x : (sub == 1) ? v.y : (sub == 2) ? v.z : v.w;
                if      (sub == 0) v.x = -INFINITY;
                else if (sub == 1) v.y = -INFINITY;
                else if (sub == 2) v.z = -INFINITY;
                else               v.w = -INFINITY;
            }
            ins4(v.x, t0, t1, t2, t3);
            ins4(v.y, t0, t1, t2, t3);
            ins4(v.z, t0, t1, t2, t3);
            ins4(v.w, t0, t1, t2, t3);
        }

        // Butterfly all-reduce across the 64-lane wave: merge sorted-4 lists.
        // XOR butterfly: groups are disjoint at every stage, each source lane
        // contributes exactly once -> correct for (non-idempotent) top-k.
        #pragma unroll
        for (int m = 1; m < 64; m <<= 1) {
            float o0 = __shfl_xor(t0, m, 64);
            float o1 = __shfl_xor(t1, m, 64);
            float o2 = __shfl_xor(t2, m, 64);
            float o3 = __shfl_xor(t3, m, 64);
            float ol = __shfl_xor(lab, m, 64);
            ins4(o0, t0, t1, t2, t3);
            ins4(o1, t0, t1, t2, t3);
            ins4(o2, t0, t1, t2, t3);
            ins4(o3, t0, t1, t2, t3);
            lab = fmaxf(lab, ol);
        }

        // loss = logsumexp([lab, t0..t3]) - lab
        float mx = fmaxf(lab, t0);            // t0 is the max of the top-4
        float s  = expf(lab - mx) + expf(t0 - mx) + expf(t1 - mx)
                 + expf(t2 - mx) + expf(t3 - mx);
        loss = logf(s) + mx - lab;
    }

    if (lane == 0) s_loss[wid] = loss;
    __syncthreads();
    if (threadIdx.x == 0) {
        float acc = 0.0f;
        #pragma unroll
        for (int w = 0; w < WAVES_PER_BLOCK; ++w) acc += s_loss[w];
        atomicAdd(out, acc * invB);           // one device-scope atomic per block
    }
}

extern "C" void kernel_launch(void* const* d_in, const int* in_sizes, int n_in,
                              void* d_out, int out_size, void* d_ws, size_t ws_size,
                              hipStream_t stream) {
    const float* logits = (const float*)d_in[0];
    const int*   labels = (const int*)d_in[1];
    float*       out    = (float*)d_out;

    const int B = in_sizes[1];
    const int C = in_sizes[0] / B;   // 1000

    // d_out is re-poisoned to 0xAA before every launch; zero it for atomicAdd.
    hipMemsetAsync(out, 0, sizeof(float), stream);

    const int grid = (B + WAVES_PER_BLOCK - 1) / WAVES_PER_BLOCK;
    topk_hard_neg_loss_kernel<<<grid, WAVES_PER_BLOCK * 64, 0, stream>>>(
        logits, labels, out, B, C, 1.0f / (float)B);
}

// Round 2
// 197.155 us; speedup vs baseline: 1.3126x; 1.3126x over previous
//
#include <hip/hip_runtime.h>
#include <math.h>

// GradientBoostingLoss: per-row top-4 hardest negatives + logsumexp, mean over rows.
// Wave-per-row, 4-deep prefetched float4 loads, bitonic butterfly top-4 merge,
// per-block partials in d_ws + second reduction kernel (NO same-address atomics).

#define WPB 4  // waves per block (256 threads)

__device__ __forceinline__ void ins4(float v, float &t0, float &t1, float &t2, float &t3) {
    // Branchless sorted-descending insert of v into (t0 >= t1 >= t2 >= t3).
    bool b0 = v > t0, b1 = v > t1, b2 = v > t2, b3 = v > t3;
    float n0 = b0 ? v  : t0;
    float n1 = b0 ? t0 : (b1 ? v : t1);
    float n2 = b1 ? t1 : (b2 ? v : t2);
    float n3 = b2 ? t2 : (b3 ? v : t3);
    t0 = n0; t1 = n1; t2 = n2; t3 = n3;
}

// Merge own sorted-desc top-4 with partner's sorted-desc top-4 -> sorted-desc top-4
// of the union. Stage 1 of Batcher bitonic merge (4 max) + 4-elt bitonic sort (4 CE).
// 12 VALU ops vs ~40 for 4x ins4.
__device__ __forceinline__ void merge4(float o0, float o1, float o2, float o3,
                                       float &t0, float &t1, float &t2, float &t3) {
    float c0 = fmaxf(t0, o3);
    float c1 = fmaxf(t1, o2);
    float c2 = fmaxf(t2, o1);
    float c3 = fmaxf(t3, o0);             // {c} = top-4 multiset, bitonic order
    float d0 = fmaxf(c0, c2), d2 = fminf(c0, c2);
    float d1 = fmaxf(c1, c3), d3 = fminf(c1, c3);
    t0 = fmaxf(d0, d1); t1 = fminf(d0, d1);
    t2 = fmaxf(d2, d3); t3 = fminf(d2, d3);
}

__device__ __forceinline__ void fix_label(float4 &v, int q, int qL, int sub, float &lab) {
    if (q == qL) {
        lab = (sub == 0) ? v.x : (sub == 1) ? v.y : (sub == 2) ? v.z : v.w;
        if      (sub == 0) v.x = -INFINITY;
        else if (sub == 1) v.y = -INFINITY;
        else if (sub == 2) v.z = -INFINITY;
        else               v.w = -INFINITY;
    }
}

__global__ __launch_bounds__(256) void topk_loss_partial(
    const float* __restrict__ logits, const int* __restrict__ labels,
    float* __restrict__ partial, int B, int C)
{
    const int wid  = threadIdx.x >> 6;
    const int lane = threadIdx.x & 63;
    const int row  = blockIdx.x * WPB + wid;

    __shared__ float s_loss[WPB];

    float loss = 0.0f;
    if (row < B) {
        const float4* rp = (const float4*)(logits + (size_t)row * (size_t)C);
        const int nq  = C >> 2;           // 250 for C=1000
        const int L   = labels[row];
        const int qL  = L >> 2;
        const int sub = L & 3;

        // 4 prefetched loads per lane (covers nq <= 256; generic tail below).
        const int q0 = lane;
        const int q1 = lane + 64;
        const int q2 = lane + 128;
        int q3 = lane + 192;
        const bool ok1 = q1 < nq, ok2 = q2 < nq, ok3 = q3 < nq;
        if (!ok3) q3 = nq - 1;            // clamped read; value replaced below

        float4 a0 = rp[q0];
        float4 a1 = ok1 ? rp[q1] : make_float4(-INFINITY,-INFINITY,-INFINITY,-INFINITY);
        float4 a2 = ok2 ? rp[q2] : make_float4(-INFINITY,-INFINITY,-INFINITY,-INFINITY);
        float4 a3 = rp[q3];

        float lab = -INFINITY;
        fix_label(a0, q0, qL, sub, lab);
        if (ok1) fix_label(a1, q1, qL, sub, lab);
        if (ok2) fix_label(a2, q2, qL, sub, lab);
        fix_label(a3, q3, qL, sub, lab);  // clamped-duplicate capture is the same value: harmless
        if (!ok3) a3 = make_float4(-INFINITY,-INFINITY,-INFINITY,-INFINITY);

        float t0 = -INFINITY, t1 = -INFINITY, t2 = -INFINITY, t3 = -INFINITY;
        ins4(a0.x,t0,t1,t2,t3); ins4(a0.y,t0,t1,t2,t3); ins4(a0.z,t0,t1,t2,t3); ins4(a0.w,t0,t1,t2,t3);
        ins4(a1.x,t0,t1,t2,t3); ins4(a1.y,t0,t1,t2,t3); ins4(a1.z,t0,t1,t2,t3); ins4(a1.w,t0,t1,t2,t3);
        ins4(a2.x,t0,t1,t2,t3); ins4(a2.y,t0,t1,t2,t3); ins4(a2.z,t0,t1,t2,t3); ins4(a2.w,t0,t1,t2,t3);
        ins4(a3.x,t0,t1,t2,t3); ins4(a3.y,t0,t1,t2,t3); ins4(a3.z,t0,t1,t2,t3); ins4(a3.w,t0,t1,t2,t3);

        // Generic tail for nq > 256 (dead for C=1000).
        for (int q = lane + 256; q < nq; q += 64) {
            float4 v = rp[q];
            fix_label(v, q, qL, sub, lab);
            ins4(v.x,t0,t1,t2,t3); ins4(v.y,t0,t1,t2,t3);
            ins4(v.z,t0,t1,t2,t3); ins4(v.w,t0,t1,t2,t3);
        }

        // Butterfly all-reduce across 64 lanes: disjoint XOR groups at each stage,
        // each source contributes exactly once -> valid for top-k.
        #pragma unroll
        for (int m = 1; m < 64; m <<= 1) {
            float o0 = __shfl_xor(t0, m, 64);
            float o1 = __shfl_xor(t1, m, 64);
            float o2 = __shfl_xor(t2, m, 64);
            float o3 = __shfl_xor(t3, m, 64);
            float ol = __shfl_xor(lab, m, 64);
            merge4(o0, o1, o2, o3, t0, t1, t2, t3);
            lab = fmaxf(lab, ol);
        }

        // loss = logsumexp([lab, t0..t3]) - lab ; t0 = max of negatives
        float mx = fmaxf(lab, t0);
        float s  = expf(lab - mx) + expf(t0 - mx) + expf(t1 - mx)
                 + expf(t2 - mx) + expf(t3 - mx);
        loss = logf(s) + mx - lab;
    }

    if (lane == 0) s_loss[wid] = loss;
    __syncthreads();
    if (threadIdx.x == 0) {
        float acc = s_loss[0] + s_loss[1] + s_loss[2] + s_loss[3];
        partial[blockIdx.x] = acc;        // one plain store per block; no atomics
    }
}

__global__ __launch_bounds__(256) void reduce_partials(
    const float* __restrict__ partial, float* __restrict__ out, int n, float invB)
{
    __shared__ float s_sum[WPB];
    float s = 0.0f;
    for (int i = threadIdx.x; i < n; i += 256) s += partial[i];

    #pragma unroll
    for (int m = 32; m >= 1; m >>= 1) s += __shfl_down(s, m, 64);

    const int wid  = threadIdx.x >> 6;
    const int lane = threadIdx.x & 63;
    if (lane == 0) s_sum[wid] = s;
    __syncthreads();
    if (threadIdx.x == 0)
        *out = (s_sum[0] + s_sum[1] + s_sum[2] + s_sum[3]) * invB;
}

extern "C" void kernel_launch(void* const* d_in, const int* in_sizes, int n_in,
                              void* d_out, int out_size, void* d_ws, size_t ws_size,
                              hipStream_t stream) {
    const float* logits = (const float*)d_in[0];
    const int*   labels = (const int*)d_in[1];
    float*       out    = (float*)d_out;
    float*       part   = (float*)d_ws;   // grid floats (32 KB for B=32768)

    const int B = in_sizes[1];
    const int C = in_sizes[0] / B;        // 1000

    const int grid = (B + WPB - 1) / WPB; // 8192
    topk_loss_partial<<<grid, WPB * 64, 0, stream>>>(logits, labels, part, B, C);
    reduce_partials<<<1, 256, 0, stream>>>(part, out, grid, 1.0f / (float)B);
}